// Round 5
// baseline (1123.995 us; speedup 1.0000x reference)
//
#include <hip/hip_runtime.h>

// FISSA forward, MI355X. One workgroup per batch element (B=1024), 512 threads
// (8 waves). Register-blocked GEMMs: lane = output column, wave wv owns rows
// {wv+8r}. All inner loops FULLY UNROLLED so LDS reads use constant-offset
// immediates (no per-iteration address math). Wave-uniform operands are
// broadcast ds_reads (bandwidth-free); c1/c2 weights are read via
// readfirstlane -> scalar (s_load) pipe. LBA branch first; LDS 51.8 KB.

#define NB 1024
#define LL 50
#define DD 64
#define LD 66   // x/a/b row stride (floats): rows 8B-aligned (264 B)
#define LDC 52  // score row stride: rows 16B-aligned (208 B)
#define NR 7
#define NEGV (-4294967295.0f)

__device__ __forceinline__ float wsum(float v) {
#pragma unroll
  for (int m = 32; m >= 1; m >>= 1) v += __shfl_xor(v, m, 64);
  return v;
}
__device__ __forceinline__ float wmax(float v) {
#pragma unroll
  for (int m = 32; m >= 1; m >>= 1) v = fmaxf(v, __shfl_xor(v, m, 64));
  return v;
}
// in-register row LayerNorm (one row across 64 lanes)
__device__ __forceinline__ float rowln(float v) {
  float m = wsum(v) * (1.f / 64.f);
  float df = v - m;
  float var = wsum(df * df) * (1.f / 64.f);
  return df / sqrtf(var + 1e-8f);
}
__device__ __forceinline__ float2 ld2(const float* p) {
  return *reinterpret_cast<const float2*>(p);
}
__device__ __forceinline__ float4 ld4(const float* p) {
  return *reinterpret_cast<const float4*>(p);
}

__global__ __launch_bounds__(512, 4) void fissa_kernel(
    const int* __restrict__ user_items, const int* __restrict__ pos_items,
    const int* __restrict__ neg_items, const float* __restrict__ pmask,
    const float* __restrict__ item_emb, const float* __restrict__ pos_emb,
    const float* __restrict__ Qs, const float* __restrict__ Ks,
    const float* __restrict__ Vs, const float* __restrict__ c1w,
    const float* __restrict__ c1b, const float* __restrict__ c2w,
    const float* __restrict__ c2b, const float* __restrict__ query,
    const float* __restrict__ Klba, const float* __restrict__ Vlba,
    const float* __restrict__ l1w, const float* __restrict__ l1b,
    const float* __restrict__ l2w, const float* __restrict__ l2b,
    const float* __restrict__ gw, const float* __restrict__ gb,
    float* __restrict__ out) {
  __shared__ float s_x[LL * LD];   // x / att / ff (in-place residuals)
  __shared__ float s_a[LL * LD];   // Kx_lba -> Qx -> Vx
  __shared__ float s_b[LL * LD];   // Vx_lba -> Kx -> h
  __shared__ float s_c[LL * LDC];  // scores
  __shared__ float s_mask[64], s_qv[64], s_glo[64], s_gw[192], s_sm[64], s_scal[2];

  const int b = blockIdx.x;
  const int tid = threadIdx.x;
  const int wv = tid >> 6, ln = tid & 63;

  int qrow[NR], qoff[NR], coff[NR], qu[NR];
  bool qok[NR];
#pragma unroll
  for (int r = 0; r < NR; ++r) {
    int q = wv + 8 * r;
    qok[r] = (q < LL);
    qrow[r] = qok[r] ? q : (LL - 1);
    qoff[r] = qrow[r] * LD;
    coff[r] = qrow[r] * LDC;
    qu[r] = __builtin_amdgcn_readfirstlane(qrow[r]);  // provably uniform row idx
  }

  // ---- small params ----
  if (tid < 64) s_mask[tid] = (tid < LL) ? pmask[b * LL + tid] : 0.f;
  else if (tid < 128) s_qv[tid - 64] = query[tid - 64];
  else if (tid < 320) s_gw[tid - 128] = gw[tid - 128];

  // ---- gather + pos emb + mask + LN (in-register) -> s_x ----
#pragma unroll
  for (int r = 0; r < NR; ++r) {
    int l = qrow[r];
    int u = user_items[b * LL + l];
    float mk = pmask[b * LL + l];
    float v = (item_emb[(size_t)u * DD + ln] + pos_emb[l * DD + ln]) * mk;
    float o = rowln(v);
    if (qok[r]) s_x[qoff[r] + ln] = o;
  }
  __syncthreads();

  // ---- LBA branch FIRST (depends only on initial LN'd input in s_x) ----
  {
    float akl[NR], avl[NR];
#pragma unroll
    for (int r = 0; r < NR; ++r) { akl[r] = 0.f; avl[r] = 0.f; }
    const float* Kc = Klba + ln;
    const float* Vc = Vlba + ln;
#pragma unroll
    for (int k = 0; k < DD; k += 2) {
      float wk0 = Kc[k * DD], wk1 = Kc[(k + 1) * DD];
      float wv0 = Vc[k * DD], wv1 = Vc[(k + 1) * DD];
#pragma unroll
      for (int r = 0; r < NR; ++r) {
        float2 xv = ld2(&s_x[qoff[r] + k]);
        akl[r] = fmaf(xv.x, wk0, akl[r]);
        akl[r] = fmaf(xv.y, wk1, akl[r]);
        avl[r] = fmaf(xv.x, wv0, avl[r]);
        avl[r] = fmaf(xv.y, wv1, avl[r]);
      }
    }
#pragma unroll
    for (int r = 0; r < NR; ++r)
      if (qok[r]) { s_a[qoff[r] + ln] = akl[r]; s_b[qoff[r] + ln] = avl[r]; }
  }
  __syncthreads();
  if (wv == 0) {  // single-wave glo stage
    float sc = -INFINITY;
    if (ln < LL) {
      float acc = 0.f;
      const float* arow = &s_a[ln * LD];
#pragma unroll
      for (int d = 0; d < DD; d += 2) {
        float2 av = ld2(&arow[d]);
        acc = fmaf(s_qv[d], av.x, acc);
        acc = fmaf(s_qv[d + 1], av.y, acc);
      }
      sc = acc;
      if (s_mask[ln] == 0.f) sc = NEGV;
    }
    float mx = wmax(sc);
    float e = (ln < LL) ? expf(sc - mx) : 0.f;
    float den = wsum(e);
    if (ln < LL) s_sm[ln] = e / den;  // softmax probs (same-wave DS ordering)
    float acc = 0.f;
#pragma unroll
    for (int l = 0; l < LL; ++l) acc = fmaf(s_sm[l], s_b[l * LD + ln], acc);
    float g = rowln(acc);  // LN(glo)
    float h = fmaxf(l1w[0] * g + l1b[0], 0.f);
    float glo = rowln(l2w[0] * h + l2b[0] + g);  // final glo
    s_glo[ln] = glo;
    float gs = wsum(glo * s_gw[64 + ln]);
    if (ln == 0) s_scal[0] = gs + gb[0];
  }
  __syncthreads();

  // ---- SAB layers ----
#pragma unroll 1
  for (int i = 0; i < 2; ++i) {
    const float* Qc = Qs + i * DD * DD + ln;
    const float* Kc = Ks + i * DD * DD + ln;
    const float* Vc = Vs + i * DD * DD + ln;

    // Qx -> s_a, Kx -> s_b
    {
      float aq[NR], ak[NR];
#pragma unroll
      for (int r = 0; r < NR; ++r) { aq[r] = 0.f; ak[r] = 0.f; }
#pragma unroll
      for (int k = 0; k < DD; k += 2) {
        float wq0 = Qc[k * DD], wq1 = Qc[(k + 1) * DD];
        float wk0 = Kc[k * DD], wk1 = Kc[(k + 1) * DD];
#pragma unroll
        for (int r = 0; r < NR; ++r) {
          float2 xv = ld2(&s_x[qoff[r] + k]);
          aq[r] = fmaf(xv.x, wq0, aq[r]);
          aq[r] = fmaf(xv.y, wq1, aq[r]);
          ak[r] = fmaf(xv.x, wk0, ak[r]);
          ak[r] = fmaf(xv.y, wk1, ak[r]);
        }
      }
#pragma unroll
      for (int r = 0; r < NR; ++r)
        if (qok[r]) { s_a[qoff[r] + ln] = aq[r]; s_b[qoff[r] + ln] = ak[r]; }
    }
    __syncthreads();

    // scores -> s_c (lane = k; raw masked scores, NO softmax)
    {
      float sc[NR];
#pragma unroll
      for (int r = 0; r < NR; ++r) sc[r] = 0.f;
      const int kk = (ln < LL) ? ln : (LL - 1);
      const float* krow = &s_b[kk * LD];
#pragma unroll
      for (int d = 0; d < DD; d += 2) {
        float2 kv = ld2(&krow[d]);
#pragma unroll
        for (int r = 0; r < NR; ++r) {
          float2 qv = ld2(&s_a[qoff[r] + d]);
          sc[r] = fmaf(qv.x, kv.x, sc[r]);
          sc[r] = fmaf(qv.y, kv.y, sc[r]);
        }
      }
      if (ln < LL) {
        float mk = s_mask[ln];
#pragma unroll
        for (int r = 0; r < NR; ++r)
          if (qok[r]) {
            float v = sc[r] * 0.125f;     // / sqrt(64)
            if (ln > qrow[r]) v = NEGV;   // causal
            if (mk == 0.f) v = NEGV;      // key mask
            v *= s_mask[qrow[r]];         // * padding_mask[q]
            s_c[coff[r] + ln] = v;
          }
      }
    }
    __syncthreads();

    // Vx -> s_a (Qx dead)
    {
      float av[NR];
#pragma unroll
      for (int r = 0; r < NR; ++r) av[r] = 0.f;
#pragma unroll
      for (int k = 0; k < DD; k += 2) {
        float wv0 = Vc[k * DD], wv1 = Vc[(k + 1) * DD];
#pragma unroll
        for (int r = 0; r < NR; ++r) {
          float2 xv = ld2(&s_x[qoff[r] + k]);
          av[r] = fmaf(xv.x, wv0, av[r]);
          av[r] = fmaf(xv.y, wv1, av[r]);
        }
      }
#pragma unroll
      for (int r = 0; r < NR; ++r)
        if (qok[r]) s_a[qoff[r] + ln] = av[r];
    }
    __syncthreads();

    // att = scores@Vx + x, LN fused -> s_x  (sc rows are broadcast b128 reads)
    {
      float at[NR];
#pragma unroll
      for (int r = 0; r < NR; ++r) at[r] = s_x[qoff[r] + ln];  // residual
#pragma unroll
      for (int k = 0; k < 48; k += 4) {
        float v0 = s_a[k * LD + ln];
        float v1 = s_a[(k + 1) * LD + ln];
        float v2 = s_a[(k + 2) * LD + ln];
        float v3 = s_a[(k + 3) * LD + ln];
#pragma unroll
        for (int r = 0; r < NR; ++r) {
          float4 sv = ld4(&s_c[coff[r] + k]);
          at[r] = fmaf(sv.x, v0, at[r]);
          at[r] = fmaf(sv.y, v1, at[r]);
          at[r] = fmaf(sv.z, v2, at[r]);
          at[r] = fmaf(sv.w, v3, at[r]);
        }
      }
      {  // k = 48, 49 remainder
        float v0 = s_a[48 * LD + ln];
        float v1 = s_a[49 * LD + ln];
#pragma unroll
        for (int r = 0; r < NR; ++r) {
          float2 sv = ld2(&s_c[coff[r] + 48]);
          at[r] = fmaf(sv.x, v0, at[r]);
          at[r] = fmaf(sv.y, v1, at[r]);
        }
      }
#pragma unroll
      for (int r = 0; r < NR; ++r) {
        float o = rowln(at[r]);
        if (qok[r]) s_x[qoff[r] + ln] = o;
      }
    }
    __syncthreads();

    // h = relu(c1 @ att + c1b) -> s_b   (c1 via uniform scalar loads)
    {
      const float* c1r[NR];
      float hh[NR];
#pragma unroll
      for (int r = 0; r < NR; ++r) {
        c1r[r] = c1w + i * LL * LL + qu[r] * LL;
        hh[r] = 0.f;
      }
#pragma unroll
      for (int j = 0; j < LL; ++j) {
        float xj = s_x[j * LD + ln];
#pragma unroll
        for (int r = 0; r < NR; ++r) hh[r] = fmaf(c1r[r][j], xj, hh[r]);
      }
#pragma unroll
      for (int r = 0; r < NR; ++r)
        if (qok[r]) s_b[qoff[r] + ln] = fmaxf(hh[r] + c1b[i * LL + qu[r]], 0.f);
    }
    __syncthreads();

    // ff = c2 @ h + c2b + att, *mask, LN fused -> s_x  (c2 via scalar loads)
    {
      const float* c2r[NR];
      float f0[NR];
#pragma unroll
      for (int r = 0; r < NR; ++r) {
        c2r[r] = c2w + i * LL * LL + qu[r] * LL;
        f0[r] = s_x[qoff[r] + ln];  // att residual (own element)
      }
#pragma unroll
      for (int j = 0; j < LL; ++j) {
        float hj = s_b[j * LD + ln];
#pragma unroll
        for (int r = 0; r < NR; ++r) f0[r] = fmaf(c2r[r][j], hj, f0[r]);
      }
#pragma unroll
      for (int r = 0; r < NR; ++r) {
        float v = (f0[r] + c2b[i * LL + qu[r]]) * s_mask[qrow[r]];
        float o = rowln(v);
        if (qok[r]) s_x[qoff[r] + ln] = o;
      }
    }
    __syncthreads();
  }

  // ---- gating + output: one wave per (pos/neg, l) row ----
  float g2c = s_scal[0];
  float gloc = s_glo[ln];
#pragma unroll 1
  for (int row = wv; row < 2 * LL; row += 8) {
    int sgn = row >= LL;
    int l = row - sgn * LL;
    int u = user_items[b * LL + l];
    int it = sgn ? neg_items[b * LL + l] : pos_items[b * LL + l];
    float ie_d = item_emb[(size_t)u * DD + ln];
    float mi_d = item_emb[(size_t)it * DD + ln];
    float logit = wsum(ie_d * s_gw[ln] + mi_d * s_gw[128 + ln]) + g2c;
    float sg = 1.f / (1.f + expf(-logit));
    float g = 1.f / (1.f + expf(-sg));  // sigmoid(sigmoid(logit))
    float od = (s_x[l * LD + ln] * g + gloc * (1.f - g)) * s_mask[l];
    float o = rowln(od);
    float res = wsum(o * mi_d);
    if (ln == 0) out[(sgn * NB + b) * LL + l] = res;
  }
}

extern "C" void kernel_launch(void* const* d_in, const int* in_sizes, int n_in,
                              void* d_out, int out_size, void* d_ws, size_t ws_size,
                              hipStream_t stream) {
  const int* user_items = (const int*)d_in[0];
  const int* pos_items = (const int*)d_in[1];
  const int* neg_items = (const int*)d_in[2];
  const float* pmask = (const float*)d_in[3];
  const float* item_emb = (const float*)d_in[4];
  const float* pos_emb = (const float*)d_in[5];
  const float* Qs = (const float*)d_in[6];
  const float* Ks = (const float*)d_in[7];
  const float* Vs = (const float*)d_in[8];
  const float* c1w = (const float*)d_in[9];
  const float* c1b = (const float*)d_in[10];
  const float* c2w = (const float*)d_in[11];
  const float* c2b = (const float*)d_in[12];
  const float* query = (const float*)d_in[13];
  const float* Klba = (const float*)d_in[14];
  const float* Vlba = (const float*)d_in[15];
  const float* l1w = (const float*)d_in[16];
  const float* l1b = (const float*)d_in[17];
  const float* l2w = (const float*)d_in[18];
  const float* l2b = (const float*)d_in[19];
  const float* gw = (const float*)d_in[20];
  const float* gb = (const float*)d_in[21];
  float* out = (float*)d_out;

  fissa_kernel<<<dim3(NB), dim3(512), 0, stream>>>(
      user_items, pos_items, neg_items, pmask, item_emb, pos_emb, Qs, Ks, Vs,
      c1w, c1b, c2w, c2b, query, Klba, Vlba, l1w, l1b, l2w, l2b, gw, gb, out);
}

// Round 6
// 342.948 us; speedup vs baseline: 3.2775x; 3.2775x over previous
//
#include <hip/hip_runtime.h>

// FISSA forward, MI355X. One workgroup per batch element (B=1024), 512 threads
// (8 waves). Register-blocked fp32 GEMMs: lane = output column, wave wv owns
// rows {wv+8r}. Wide LDS access: x rows read as b128 broadcasts (LD=68,
// 16B-aligned rows); Kx stored TRANSPOSED (LDT=51, odd stride -> conflict-free
// lane reads) so the scores loop is stride-1; score/c-weight rows read as b128
// broadcasts (LDC=52). Buffers sequentially reused -> LDS 51.7 KB.
// No launch-bounds squeeze (R4), no pointer arrays / full unroll (R5 spills).

#define NB 1024
#define LL 50
#define DD 64
#define LD 68   // x/b row stride (floats): rows 16B-aligned for b128 broadcast
#define LDT 51  // Kx^T row stride: odd -> transposed writes/lane reads 2-way max
#define LDC 52  // score/c row stride: rows 16B-aligned for b128 broadcast
#define NR 7
#define NEGV (-4294967295.0f)

__device__ __forceinline__ float wsum(float v) {
#pragma unroll
  for (int m = 32; m >= 1; m >>= 1) v += __shfl_xor(v, m, 64);
  return v;
}
__device__ __forceinline__ float wmax(float v) {
#pragma unroll
  for (int m = 32; m >= 1; m >>= 1) v = fmaxf(v, __shfl_xor(v, m, 64));
  return v;
}
// in-register row LayerNorm (one row across 64 lanes)
__device__ __forceinline__ float rowln(float v) {
  float m = wsum(v) * (1.f / 64.f);
  float df = v - m;
  float var = wsum(df * df) * (1.f / 64.f);
  return df / sqrtf(var + 1e-8f);
}
__device__ __forceinline__ float2 ld2(const float* p) {
  return *reinterpret_cast<const float2*>(p);
}
__device__ __forceinline__ float4 ld4(const float* p) {
  return *reinterpret_cast<const float4*>(p);
}

__global__ __launch_bounds__(512, 2) void fissa_kernel(
    const int* __restrict__ user_items, const int* __restrict__ pos_items,
    const int* __restrict__ neg_items, const float* __restrict__ pmask,
    const float* __restrict__ item_emb, const float* __restrict__ pos_emb,
    const float* __restrict__ Qs, const float* __restrict__ Ks,
    const float* __restrict__ Vs, const float* __restrict__ c1w,
    const float* __restrict__ c1b, const float* __restrict__ c2w,
    const float* __restrict__ c2b, const float* __restrict__ query,
    const float* __restrict__ Klba, const float* __restrict__ Vlba,
    const float* __restrict__ l1w, const float* __restrict__ l1b,
    const float* __restrict__ l2w, const float* __restrict__ l2b,
    const float* __restrict__ gw, const float* __restrict__ gb,
    float* __restrict__ out) {
  __shared__ __align__(16) float s_x[LL * LD];        // x / att / ff (in-place)
  __shared__ __align__(16) float s_b[LL * LD];        // LBA-Vx -> Qx -> Vx -> h
  __shared__ __align__(16) float s_kt[DD * LDT + 64]; // Kx^T (pad: lanes 50-63 OOB-read)
  __shared__ __align__(16) float s_c[LL * LDC];       // scores -> c1 -> c2
  __shared__ __align__(16) float s_mask[64], s_qv[64], s_glo[64], s_sm[64],
      s_bias[64], s_gw[192], s_scal[2];

  const int b = blockIdx.x;
  const int tid = threadIdx.x;
  const int wv = tid >> 6, ln = tid & 63;

  int qrow[NR], qoff[NR], coff[NR];
  bool qok[NR];
#pragma unroll
  for (int r = 0; r < NR; ++r) {
    int q = wv + 8 * r;
    qok[r] = (q < LL);
    qrow[r] = qok[r] ? q : (LL - 1);
    qoff[r] = qrow[r] * LD;
    coff[r] = qrow[r] * LDC;
  }

  // ---- small params ----
  if (tid < 64) s_mask[tid] = (tid < LL) ? pmask[b * LL + tid] : 0.f;
  else if (tid < 128) s_qv[tid - 64] = query[tid - 64];
  else if (tid < 320) s_gw[tid - 128] = gw[tid - 128];

  // ---- gather + pos emb + mask + LN (in-register) -> s_x ----
#pragma unroll
  for (int r = 0; r < NR; ++r) {
    int l = qrow[r];
    int u = user_items[b * LL + l];
    float mk = pmask[b * LL + l];
    float v = (item_emb[(size_t)u * DD + ln] + pos_emb[l * DD + ln]) * mk;
    float o = rowln(v);
    if (qok[r]) s_x[qoff[r] + ln] = o;
  }
  __syncthreads();

  // ---- LBA projections FIRST: Kx^T -> s_kt, Vx -> s_b ----
  {
    float akl[NR], avl[NR];
#pragma unroll
    for (int r = 0; r < NR; ++r) { akl[r] = 0.f; avl[r] = 0.f; }
    const float* Kc = Klba + ln;
    const float* Vc = Vlba + ln;
#pragma unroll 2
    for (int kc = 0; kc < DD; kc += 4) {
      float wk0 = Kc[kc * DD], wk1 = Kc[(kc + 1) * DD];
      float wk2 = Kc[(kc + 2) * DD], wk3 = Kc[(kc + 3) * DD];
      float wv0 = Vc[kc * DD], wv1 = Vc[(kc + 1) * DD];
      float wv2 = Vc[(kc + 2) * DD], wv3 = Vc[(kc + 3) * DD];
#pragma unroll
      for (int r = 0; r < NR; ++r) {
        float4 xv = ld4(&s_x[qoff[r] + kc]);
        akl[r] = fmaf(xv.x, wk0, fmaf(xv.y, wk1, fmaf(xv.z, wk2, fmaf(xv.w, wk3, akl[r]))));
        avl[r] = fmaf(xv.x, wv0, fmaf(xv.y, wv1, fmaf(xv.z, wv2, fmaf(xv.w, wv3, avl[r]))));
      }
    }
#pragma unroll
    for (int r = 0; r < NR; ++r)
      if (qok[r]) {
        s_kt[ln * LDT + qrow[r]] = akl[r];  // transposed: row d=ln, col l
        s_b[qoff[r] + ln] = avl[r];
      }
  }
  __syncthreads();

  // ---- single-wave glo stage ----
  if (wv == 0) {
    float sc = -INFINITY;
    {
      float acc = 0.f;
#pragma unroll 4
      for (int d = 0; d < DD; ++d) acc = fmaf(s_qv[d], s_kt[d * LDT + ln], acc);
      sc = acc;
      if (ln >= LL || s_mask[ln] == 0.f) sc = (ln < LL) ? NEGV : -INFINITY;
    }
    float mx = wmax(sc);
    float e = (ln < LL) ? expf(sc - mx) : 0.f;
    float den = wsum(e);
    if (ln < LL) s_sm[ln] = e / den;  // softmax probs (same-wave DS ordering)
    float acc = 0.f;
#pragma unroll 2
    for (int l = 0; l < LL; ++l) acc = fmaf(s_sm[l], s_b[l * LD + ln], acc);
    float g = rowln(acc);  // LN(glo)
    float h = fmaxf(l1w[0] * g + l1b[0], 0.f);
    float glo = rowln(l2w[0] * h + l2b[0] + g);  // final glo
    s_glo[ln] = glo;
    float gs = wsum(glo * s_gw[64 + ln]);
    if (ln == 0) s_scal[0] = gs + gb[0];
  }
  __syncthreads();

  // ---- SAB layers ----
#pragma unroll 1
  for (int i = 0; i < 2; ++i) {
    const float* Qc = Qs + i * DD * DD + ln;
    const float* Kc = Ks + i * DD * DD + ln;
    const float* Vc = Vs + i * DD * DD + ln;

    // Qx -> s_b, Kx^T -> s_kt
    {
      float aq[NR], ak[NR];
#pragma unroll
      for (int r = 0; r < NR; ++r) { aq[r] = 0.f; ak[r] = 0.f; }
#pragma unroll 2
      for (int kc = 0; kc < DD; kc += 4) {
        float wq0 = Qc[kc * DD], wq1 = Qc[(kc + 1) * DD];
        float wq2 = Qc[(kc + 2) * DD], wq3 = Qc[(kc + 3) * DD];
        float wk0 = Kc[kc * DD], wk1 = Kc[(kc + 1) * DD];
        float wk2 = Kc[(kc + 2) * DD], wk3 = Kc[(kc + 3) * DD];
#pragma unroll
        for (int r = 0; r < NR; ++r) {
          float4 xv = ld4(&s_x[qoff[r] + kc]);
          aq[r] = fmaf(xv.x, wq0, fmaf(xv.y, wq1, fmaf(xv.z, wq2, fmaf(xv.w, wq3, aq[r]))));
          ak[r] = fmaf(xv.x, wk0, fmaf(xv.y, wk1, fmaf(xv.z, wk2, fmaf(xv.w, wk3, ak[r]))));
        }
      }
#pragma unroll
      for (int r = 0; r < NR; ++r)
        if (qok[r]) {
          s_b[qoff[r] + ln] = aq[r];
          s_kt[ln * LDT + qrow[r]] = ak[r];
        }
    }
    __syncthreads();

    // scores -> s_c (lane = k; Qx b128 broadcasts, Kx^T stride-1 lane reads)
    {
      float sc[NR];
#pragma unroll
      for (int r = 0; r < NR; ++r) sc[r] = 0.f;
#pragma unroll 2
      for (int dc = 0; dc < DD; dc += 4) {
        float k0 = s_kt[dc * LDT + ln];
        float k1 = s_kt[(dc + 1) * LDT + ln];
        float k2 = s_kt[(dc + 2) * LDT + ln];
        float k3 = s_kt[(dc + 3) * LDT + ln];
#pragma unroll
        for (int r = 0; r < NR; ++r) {
          float4 qv = ld4(&s_b[qoff[r] + dc]);
          sc[r] = fmaf(qv.x, k0, fmaf(qv.y, k1, fmaf(qv.z, k2, fmaf(qv.w, k3, sc[r]))));
        }
      }
      if (ln < LL) {
        float mk = s_mask[ln];
#pragma unroll
        for (int r = 0; r < NR; ++r)
          if (qok[r]) {
            float v = sc[r] * 0.125f;     // / sqrt(64)
            if (ln > qrow[r]) v = NEGV;   // causal
            if (mk == 0.f) v = NEGV;      // key mask
            v *= s_mask[qrow[r]];         // * padding_mask[q]
            s_c[coff[r] + ln] = v;
          }
      }
    }
    __syncthreads();

    // Vx -> s_b (Qx dead after scores)
    {
      float av[NR];
#pragma unroll
      for (int r = 0; r < NR; ++r) av[r] = 0.f;
#pragma unroll 2
      for (int kc = 0; kc < DD; kc += 4) {
        float wv0 = Vc[kc * DD], wv1 = Vc[(kc + 1) * DD];
        float wv2 = Vc[(kc + 2) * DD], wv3 = Vc[(kc + 3) * DD];
#pragma unroll
        for (int r = 0; r < NR; ++r) {
          float4 xv = ld4(&s_x[qoff[r] + kc]);
          av[r] = fmaf(xv.x, wv0, fmaf(xv.y, wv1, fmaf(xv.z, wv2, fmaf(xv.w, wv3, av[r]))));
        }
      }
#pragma unroll
      for (int r = 0; r < NR; ++r)
        if (qok[r]) s_b[qoff[r] + ln] = av[r];
    }
    __syncthreads();

    // att = scores@Vx + x, LN fused -> s_x (sc rows b128 broadcast)
    {
      float at[NR];
#pragma unroll
      for (int r = 0; r < NR; ++r) at[r] = s_x[qoff[r] + ln];  // residual
#pragma unroll 2
      for (int k = 0; k < 48; k += 4) {
        float v0 = s_b[k * LD + ln];
        float v1 = s_b[(k + 1) * LD + ln];
        float v2 = s_b[(k + 2) * LD + ln];
        float v3 = s_b[(k + 3) * LD + ln];
#pragma unroll
        for (int r = 0; r < NR; ++r) {
          float4 sv = ld4(&s_c[coff[r] + k]);
          at[r] = fmaf(sv.x, v0, fmaf(sv.y, v1, fmaf(sv.z, v2, fmaf(sv.w, v3, at[r]))));
        }
      }
      {  // k = 48, 49 remainder
        float v0 = s_b[48 * LD + ln];
        float v1 = s_b[49 * LD + ln];
#pragma unroll
        for (int r = 0; r < NR; ++r) {
          float2 sv = ld2(&s_c[coff[r] + 48]);
          at[r] = fmaf(sv.x, v0, fmaf(sv.y, v1, at[r]));
        }
      }
#pragma unroll
      for (int r = 0; r < NR; ++r) {
        float o = rowln(at[r]);
        if (qok[r]) s_x[qoff[r] + ln] = o;
      }
    }
    __syncthreads();

    // stage c1 -> s_c, c1b -> s_bias
    for (int e = tid; e < LL * LL; e += 512) {
      int q = e / LL;
      s_c[q * LDC + (e - q * LL)] = c1w[i * LL * LL + e];
    }
    if (tid < LL) s_bias[tid] = c1b[i * LL + tid];
    __syncthreads();

    // h = relu(c1 @ att + c1b) -> s_b (c1 rows b128 broadcast)
    {
      float hh[NR];
#pragma unroll
      for (int r = 0; r < NR; ++r) hh[r] = 0.f;
#pragma unroll 2
      for (int j = 0; j < 48; j += 4) {
        float x0 = s_x[j * LD + ln];
        float x1 = s_x[(j + 1) * LD + ln];
        float x2 = s_x[(j + 2) * LD + ln];
        float x3 = s_x[(j + 3) * LD + ln];
#pragma unroll
        for (int r = 0; r < NR; ++r) {
          float4 cv = ld4(&s_c[coff[r] + j]);
          hh[r] = fmaf(cv.x, x0, fmaf(cv.y, x1, fmaf(cv.z, x2, fmaf(cv.w, x3, hh[r]))));
        }
      }
      {  // j = 48, 49
        float x0 = s_x[48 * LD + ln];
        float x1 = s_x[49 * LD + ln];
#pragma unroll
        for (int r = 0; r < NR; ++r) {
          float2 cv = ld2(&s_c[coff[r] + 48]);
          hh[r] = fmaf(cv.x, x0, fmaf(cv.y, x1, hh[r]));
        }
      }
#pragma unroll
      for (int r = 0; r < NR; ++r)
        if (qok[r]) s_b[qoff[r] + ln] = fmaxf(hh[r] + s_bias[qrow[r]], 0.f);
    }
    __syncthreads();

    // stage c2 -> s_c, c2b -> s_bias
    for (int e = tid; e < LL * LL; e += 512) {
      int q = e / LL;
      s_c[q * LDC + (e - q * LL)] = c2w[i * LL * LL + e];
    }
    if (tid < LL) s_bias[tid] = c2b[i * LL + tid];
    __syncthreads();

    // ff = c2 @ h + c2b + att, *mask, LN fused -> s_x
    {
      float f0[NR];
#pragma unroll
      for (int r = 0; r < NR; ++r) f0[r] = s_x[qoff[r] + ln];  // att residual
#pragma unroll 2
      for (int j = 0; j < 48; j += 4) {
        float h0 = s_b[j * LD + ln];
        float h1 = s_b[(j + 1) * LD + ln];
        float h2 = s_b[(j + 2) * LD + ln];
        float h3 = s_b[(j + 3) * LD + ln];
#pragma unroll
        for (int r = 0; r < NR; ++r) {
          float4 cv = ld4(&s_c[coff[r] + j]);
          f0[r] = fmaf(cv.x, h0, fmaf(cv.y, h1, fmaf(cv.z, h2, fmaf(cv.w, h3, f0[r]))));
        }
      }
      {  // j = 48, 49
        float h0 = s_b[48 * LD + ln];
        float h1 = s_b[49 * LD + ln];
#pragma unroll
        for (int r = 0; r < NR; ++r) {
          float2 cv = ld2(&s_c[coff[r] + 48]);
          f0[r] = fmaf(cv.x, h0, fmaf(cv.y, h1, f0[r]));
        }
      }
#pragma unroll
      for (int r = 0; r < NR; ++r) {
        float v = (f0[r] + s_bias[qrow[r]]) * s_mask[qrow[r]];
        float o = rowln(v);
        if (qok[r]) s_x[qoff[r] + ln] = o;
      }
    }
    __syncthreads();
  }

  // ---- gating + output: one wave per (pos/neg, l) row ----
  float g2c = s_scal[0];
  float gloc = s_glo[ln];
#pragma unroll 1
  for (int row = wv; row < 2 * LL; row += 8) {
    int sgn = row >= LL;
    int l = row - sgn * LL;
    int u = user_items[b * LL + l];
    int it = sgn ? neg_items[b * LL + l] : pos_items[b * LL + l];
    float ie_d = item_emb[(size_t)u * DD + ln];
    float mi_d = item_emb[(size_t)it * DD + ln];
    float logit = wsum(ie_d * s_gw[ln] + mi_d * s_gw[128 + ln]) + g2c;
    float sg = 1.f / (1.f + expf(-logit));
    float g = 1.f / (1.f + expf(-sg));  // sigmoid(sigmoid(logit))
    float od = (s_x[l * LD + ln] * g + gloc * (1.f - g)) * s_mask[l];
    float o = rowln(od);
    float res = wsum(o * mi_d);
    if (ln == 0) out[(sgn * NB + b) * LL + l] = res;
  }
}

extern "C" void kernel_launch(void* const* d_in, const int* in_sizes, int n_in,
                              void* d_out, int out_size, void* d_ws, size_t ws_size,
                              hipStream_t stream) {
  const int* user_items = (const int*)d_in[0];
  const int* pos_items = (const int*)d_in[1];
  const int* neg_items = (const int*)d_in[2];
  const float* pmask = (const float*)d_in[3];
  const float* item_emb = (const float*)d_in[4];
  const float* pos_emb = (const float*)d_in[5];
  const float* Qs = (const float*)d_in[6];
  const float* Ks = (const float*)d_in[7];
  const float* Vs = (const float*)d_in[8];
  const float* c1w = (const float*)d_in[9];
  const float* c1b = (const float*)d_in[10];
  const float* c2w = (const float*)d_in[11];
  const float* c2b = (const float*)d_in[12];
  const float* query = (const float*)d_in[13];
  const float* Klba = (const float*)d_in[14];
  const float* Vlba = (const float*)d_in[15];
  const float* l1w = (const float*)d_in[16];
  const float* l1b = (const float*)d_in[17];
  const float* l2w = (const float*)d_in[18];
  const float* l2b = (const float*)d_in[19];
  const float* gw = (const float*)d_in[20];
  const float* gb = (const float*)d_in[21];
  float* out = (float*)d_out;

  fissa_kernel<<<dim3(NB), dim3(512), 0, stream>>>(
      user_items, pos_items, neg_items, pmask, item_emb, pos_emb, Qs, Ks, Vs,
      c1w, c1b, c2w, c2b, query, Klba, Vlba, l1w, l1b, l2w, l2b, gw, gb, out);
}